// Round 11
// baseline (422.474 us; speedup 1.0000x reference)
//
#include <hip/hip_runtime.h>
#include <cstdint>
#include <cstddef>

#define NN 50000
#define HD 256
#define NCH 3

typedef __attribute__((ext_vector_type(8))) short shortx8;
typedef __attribute__((ext_vector_type(4))) float floatx4;
typedef __attribute__((ext_vector_type(16))) float floatx16;

__device__ __forceinline__ unsigned short f2bf(float x) {
    union { float f; uint32_t u; } v; v.f = x;
    uint32_t r = v.u + 0x7fffu + ((v.u >> 16) & 1u);   // RNE
    return (unsigned short)(r >> 16);
}
__device__ __forceinline__ float bf2f(unsigned short u) {
    union { uint32_t u; float f; } v; v.u = ((uint32_t)u) << 16; return v.f;
}
__device__ __forceinline__ uint32_t cvtpk(float a, float b) {
    uint32_t r;
    asm("v_cvt_pk_bf16_f32 %0, %1, %2" : "=v"(r) : "v"(a), "v"(b));
    return r;
}
__device__ __forceinline__ float sigf(float x) {
    return 1.0f / (1.0f + __expf(-x));
}
__device__ __forceinline__ float tanhfast(float x) {
    return 1.0f - 2.0f / (__expf(2.0f * x) + 1.0f);
}
__device__ __forceinline__ floatx16 mfma32(shortx8 a, shortx8 b, floatx16 c) {
    return __builtin_amdgcn_mfma_f32_32x32x16_bf16(a, b, c, 0, 0, 0);
}

// ===========================================================================
// SPLIT PATH
// Combined weight matrix W' [768 K x 1536 cols], bf16 fragments (32x32x16).
//   cols 0..767    : F, child-major (col d*256+c <- U_f[d][c]); K-support only
//                    k in [d*256, d*256+256) -> stored sparse (16 ks/tile).
//   cols 768..1535 : I|O|U, K=768 (k=d*256+k' <- U_iou[d][g*256+c][k']).
// Fragment file: F tiles t(0..23) x ksl(0..15) at fg = t*16+ksl;
//                IOU tiles t2(0..23) x ksl(0..47) at fg = 384 + t2*48 + ksl.
// Per fragment (64 lanes x 8 bf16): wcol = tile*32 + (lane&31),
//                                   k = ksl*16 + (lane>>5)*8 + e.
// ===========================================================================
__global__ void prep_split(const float* __restrict__ U_f,
                           const float* __restrict__ U_iou,
                           unsigned short* __restrict__ wsB) {
    int idx  = blockIdx.x * 256 + threadIdx.x;   // 98304 total
    int lane = idx & 63;
    int fg   = idx >> 6;
    const float* src;
    if (fg < 384) {                      // F (block-diagonal, dense-in-K'=256)
        int t   = fg >> 4;
        int ksl = fg & 15;
        int d   = t >> 3;
        int c   = t * 32 + (lane & 31) - d * 256;     // local col in [0,256)
        int kk  = ksl * 16 + (lane >> 5) * 8;         // local k in [0,256)
        src = U_f + ((size_t)d * 256 + c) * 256 + kk;
    } else {                             // IOU
        int fg2 = fg - 384;
        int t2  = fg2 / 48;
        int ksl = fg2 % 48;
        int gc  = t2 * 32 + (lane & 31);              // 0..767
        int g   = gc >> 8;
        int c   = gc & 255;
        int k   = ksl * 16 + (lane >> 5) * 8;         // 0..767
        int d   = k >> 8;
        int kk  = k & 255;
        src = U_iou + ((size_t)d * 768 + g * 256 + c) * 256 + kk;
    }
    shortx8 o;
    #pragma unroll
    for (int e = 0; e < 8; ++e) o[e] = (short)f2bf(src[e]);
    reinterpret_cast<shortx8*>(wsB)[idx] = o;
}

// ---------------------------------------------------------------------------
// GEMM: logits[row][1536] (bf16) = nh[row] (K=768) x W'. 256 thr = 4 waves,
// BM=128 nodes, BN=128 cols (wave = one 32-col tile x 4 node-tiles),
// BK=64, double-buffered 32 KiB LDS -> 4 blocks/CU. F col-blocks (cb<6)
// run K=256 (4 steps); IOU col-blocks K=768 (12 steps).
// Swapped-operand MFMA (A=weights, B=nh): lane -> node=lane&31,
// cols tile*32 + 4*(lane>>5) + 8q + r (r8-verified C/D mapping).
// ---------------------------------------------------------------------------
__global__ __launch_bounds__(256, 4) void gemm_logits(
    const float* __restrict__ nh,              // [NN][768]
    const unsigned short* __restrict__ wsB,
    unsigned short* __restrict__ logits,       // [count][1536] bf16
    int node_base, int count)
{
    __shared__ unsigned short sA[2][128 * 64]; // 2 x 16 KiB (128 nodes x 64 k)

    const int tid = threadIdx.x;
    const int bid = blockIdx.x;
    const int cb  = bid % 12;
    const int mb  = bid / 12;
    const int nb  = node_base + mb * 128;

    const int lane = tid & 63;
    const int cg   = tid >> 6;
    const int nl   = lane & 31;
    const int hi   = lane >> 5;
    const int swz  = nl & 7;

    const bool isF   = (cb < 6);
    const int  dch   = cb >> 1;
    const int  kbase = isF ? dch * 256 : 0;
    const int  nsteps = isF ? 4 : 12;
    const int  tF  = cb * 4 + cg;
    const int  t2  = (cb - 6) * 4 + cg;
    const int  fragbase = isF ? (tF * 16) : (384 + t2 * 48);
    const int  colbase  = (isF ? (tF * 32) : (768 + t2 * 32)) + hi * 4;

    const shortx8* Bfr = reinterpret_cast<const shortx8*>(wsB);

    floatx16 acc[4];
    #pragma unroll
    for (int nt = 0; nt < 4; ++nt)
        #pragma unroll
        for (int t = 0; t < 16; ++t) acc[nt][t] = 0.0f;

#define STAGE(S, B)                                                          \
    {                                                                        \
        _Pragma("unroll 4")                                                  \
        for (int i = 0; i < 8; ++i) {                                        \
            int flat = i * 256 + tid;                                        \
            int node = flat >> 4;                                            \
            int kc   = flat & 15;                                            \
            int gn   = nb + node;                                            \
            uint2 wv; wv.x = 0u; wv.y = 0u;                                  \
            if (gn < NN) {                                                   \
                float4 v = *reinterpret_cast<const float4*>(                 \
                    nh + (size_t)gn * (NCH * HD) + kbase + (S) * 64 + kc * 4);\
                wv.x = cvtpk(v.x, v.y);                                      \
                wv.y = cvtpk(v.z, v.w);                                      \
            }                                                                \
            int byt = node * 128 + (((kc >> 1) ^ (node & 7)) * 16)           \
                      + (kc & 1) * 8;                                        \
            *reinterpret_cast<uint2*>(                                       \
                reinterpret_cast<char*>(&sA[(B)][0]) + byt) = wv;            \
        }                                                                    \
    }

    STAGE(0, 0);
    __syncthreads();
    for (int s = 0; s < nsteps; ++s) {
        if (s + 1 < nsteps) STAGE(s + 1, (s + 1) & 1);
        const unsigned short* buf = &sA[s & 1][0];
        #pragma unroll
        for (int it = 0; it < 4; ++it) {
            shortx8 a = Bfr[(fragbase + s * 4 + it) * 64 + lane];
            int ch = (it * 2 + hi) ^ swz;
            #pragma unroll
            for (int nt = 0; nt < 4; ++nt) {
                shortx8 b = *reinterpret_cast<const shortx8*>(
                    buf + (nt * 32 + nl) * 64 + ch * 8);
                acc[nt] = mfma32(a, b, acc[nt]);
            }
        }
        __syncthreads();
    }
#undef STAGE

    // epilogue: bf16 logits, 8 B per (nt,q)
    #pragma unroll
    for (int nt = 0; nt < 4; ++nt) {
        int gn = nb + nt * 32 + nl;
        if (gn < node_base + count) {
            unsigned short* lr = logits + (size_t)(gn - node_base) * 1536;
            #pragma unroll
            for (int q = 0; q < 4; ++q) {
                uint2 wv;
                wv.x = cvtpk(acc[nt][q * 4 + 0], acc[nt][q * 4 + 1]);
                wv.y = cvtpk(acc[nt][q * 4 + 2], acc[nt][q * 4 + 3]);
                *reinterpret_cast<uint2*>(lr + colbase + q * 8) = wv;
            }
        }
    }
}

// ---------------------------------------------------------------------------
// Elementwise: pure streaming, grid-stride, all coalesced.
// thread item = (row, 4 cols). Reads logits bf16 (F x3, I, O, U),
// ncc x3, f_in, iou_in x3; writes h, c.
// ---------------------------------------------------------------------------
__global__ __launch_bounds__(256) void ew_kernel(
    const unsigned short* __restrict__ logits, // [count][1536]
    const float* __restrict__ ncc,             // [NN][768]
    const float* __restrict__ f_in,            // [NN][256]
    const float* __restrict__ iou_in,          // [NN][768]
    float* __restrict__ out,                   // h [NN][256], c [NN][256]
    int node_base, int count)
{
    int total = count * 64;
    for (int id = blockIdx.x * 256 + threadIdx.x; id < total;
         id += gridDim.x * 256) {
        int row = id >> 6;
        int col = (id & 63) * 4;
        int gn  = node_base + row;
        const unsigned short* lr = logits + (size_t)row * 1536;

        floatx4 fi = *reinterpret_cast<const floatx4*>(
            f_in + (size_t)gn * HD + col);
        float cagg[4] = {0.f, 0.f, 0.f, 0.f};
        #pragma unroll
        for (int d = 0; d < 3; ++d) {
            ushort4 fb = *reinterpret_cast<const ushort4*>(lr + d * 256 + col);
            floatx4 nc4 = *reinterpret_cast<const floatx4*>(
                ncc + (size_t)gn * 768 + d * 256 + col);
            cagg[0] += sigf(bf2f(fb.x) + fi[0]) * nc4[0];
            cagg[1] += sigf(bf2f(fb.y) + fi[1]) * nc4[1];
            cagg[2] += sigf(bf2f(fb.z) + fi[2]) * nc4[2];
            cagg[3] += sigf(bf2f(fb.w) + fi[3]) * nc4[3];
        }
        ushort4 ib = *reinterpret_cast<const ushort4*>(lr +  768 + col);
        ushort4 ob = *reinterpret_cast<const ushort4*>(lr + 1024 + col);
        ushort4 ub = *reinterpret_cast<const ushort4*>(lr + 1280 + col);
        size_t iob = (size_t)gn * 768 + col;
        floatx4 i4 = *reinterpret_cast<const floatx4*>(iou_in + iob);
        floatx4 o4 = *reinterpret_cast<const floatx4*>(iou_in + iob + 256);
        floatx4 u4 = *reinterpret_cast<const floatx4*>(iou_in + iob + 512);
        float iv[4] = {bf2f(ib.x), bf2f(ib.y), bf2f(ib.z), bf2f(ib.w)};
        float ov[4] = {bf2f(ob.x), bf2f(ob.y), bf2f(ob.z), bf2f(ob.w)};
        float uv[4] = {bf2f(ub.x), bf2f(ub.y), bf2f(ub.z), bf2f(ub.w)};
        floatx4 cc, hh;
        #pragma unroll
        for (int r = 0; r < 4; ++r) {
            float c = sigf(iv[r] + 2.0f * i4[r]) * tanhfast(uv[r] + 2.0f * u4[r])
                      + cagg[r];
            cc[r] = c;
            hh[r] = sigf(ov[r] + 2.0f * o4[r]) * tanhfast(c);
        }
        *reinterpret_cast<floatx4*>(out + (size_t)gn * HD + col) = hh;
        *reinterpret_cast<floatx4*>(out + (size_t)(NN + gn) * HD + col) = cc;
    }
}

// ===========================================================================
// FALLBACK PATH (r8 fused kernel, verified 283 us) -- used if ws too small.
// ===========================================================================
__global__ void prep_fused32(const float* __restrict__ U_f,
                             const float* __restrict__ U_iou,
                             unsigned short* __restrict__ wsB) {
    int idx = blockIdx.x * 256 + threadIdx.x;
    int lane = idx & 63;
    int ks   = (idx >> 6) & 15;
    int tile = (idx >> 10) & 31;
    int d    = idx >> 15;
    if (d >= NCH) return;
    int col = tile * 32 + (lane & 31);
    int k0  = ks * 16 + (lane >> 5) * 8;
    const float* src = (col < 256)
        ? (U_f   + (((size_t)d * 256 + col)         * 256 + k0))
        : (U_iou + (((size_t)d * 768 + (col - 256)) * 256 + k0));
    shortx8 o;
    #pragma unroll
    for (int e = 0; e < 8; ++e) o[e] = (short)f2bf(src[e]);
    reinterpret_cast<shortx8*>(wsB)[idx] = o;
}

__global__ __launch_bounds__(512, 4) void fused_main(
    const float* __restrict__ nh, const float* __restrict__ ncc,
    const float* __restrict__ f_in, const float* __restrict__ iou_in,
    const unsigned short* __restrict__ wsB, float* __restrict__ out)
{
    __shared__ unsigned short sA[NCH * 32 * 32 * 8];
    const int tid  = threadIdx.x;
    const int nb   = blockIdx.x * 32;
    const int lane = tid & 63;
    const int cg   = tid >> 6;
    const int nl   = lane & 31;
    const int hi   = lane >> 5;
    const int colb = cg * 32 + hi * 4;
    const shortx8* Bfr = reinterpret_cast<const shortx8*>(wsB);
    #pragma unroll
    for (int i = 0; i < 6; ++i) {
        int c = i * 512 + tid;
        int d = c >> 10, node = (c >> 5) & 31, slot = c & 31;
        int gn = nb + node;
        shortx8 o;
        if (gn < NN) {
            const float4* q = reinterpret_cast<const float4*>(
                nh + ((size_t)gn * (NCH * HD) + d * HD + slot * 8));
            float4 a = q[0], b = q[1];
            union { uint32_t u[4]; shortx8 v; } t;
            t.u[0] = cvtpk(a.x, a.y); t.u[1] = cvtpk(a.z, a.w);
            t.u[2] = cvtpk(b.x, b.y); t.u[3] = cvtpk(b.z, b.w);
            o = t.v;
        } else {
            for (int e = 0; e < 8; ++e) o[e] = 0;
        }
        int idx = (d * 32 + node) * 32 + (slot ^ (node & 7));
        *reinterpret_cast<shortx8*>(&sA[idx * 8]) = o;
    }
    __syncthreads();
    const int  n     = nb + nl;
    const bool valid = (n < NN);
    const int  nc_   = valid ? n : (NN - 1);
    ushort4 finb[4];
    #pragma unroll
    for (int q = 0; q < 4; ++q) {
        floatx4 v = *reinterpret_cast<const floatx4*>(
            f_in + (size_t)nc_ * HD + colb + q * 8);
        finb[q] = ushort4{f2bf(v[0]), f2bf(v[1]), f2bf(v[2]), f2bf(v[3])};
    }
    float cagg[16];
    #pragma unroll
    for (int t = 0; t < 16; ++t) cagg[t] = 0.0f;
    floatx16 accI, accO, accU;
    #pragma unroll
    for (int t = 0; t < 16; ++t) { accI[t] = 0.f; accO[t] = 0.f; accU[t] = 0.f; }
    const int nsw = nl & 7;
    #pragma unroll 1
    for (int d = 0; d < NCH; ++d) {
        floatx16 accF;
        #pragma unroll
        for (int t = 0; t < 16; ++t) accF[t] = 0.0f;
        #pragma unroll 2
        for (int ks = 0; ks < 16; ++ks) {
            shortx8 aF = Bfr[((d * 32 +      cg) * 16 + ks) * 64 + lane];
            shortx8 aI = Bfr[((d * 32 +  8 + cg) * 16 + ks) * 64 + lane];
            shortx8 aO = Bfr[((d * 32 + 16 + cg) * 16 + ks) * 64 + lane];
            shortx8 aU = Bfr[((d * 32 + 24 + cg) * 16 + ks) * 64 + lane];
            int ch = (ks * 2 + hi) ^ nsw;
            shortx8 b = *reinterpret_cast<const shortx8*>(
                &sA[((d * 32 + nl) * 32 + ch) * 8]);
            accF = mfma32(aF, b, accF);
            accI = mfma32(aI, b, accI);
            accO = mfma32(aO, b, accO);
            accU = mfma32(aU, b, accU);
        }
        #pragma unroll
        for (int q = 0; q < 4; ++q) {
            floatx4 ncr = *reinterpret_cast<const floatx4*>(
                ncc + (size_t)nc_ * (NCH * HD) + d * HD + colb + q * 8);
            cagg[q*4+0] += sigf(accF[q*4+0] + bf2f(finb[q].x)) * ncr[0];
            cagg[q*4+1] += sigf(accF[q*4+1] + bf2f(finb[q].y)) * ncr[1];
            cagg[q*4+2] += sigf(accF[q*4+2] + bf2f(finb[q].z)) * ncr[2];
            cagg[q*4+3] += sigf(accF[q*4+3] + bf2f(finb[q].w)) * ncr[3];
        }
    }
    if (valid) {
        #pragma unroll
        for (int q = 0; q < 4; ++q) {
            int col = colb + q * 8;
            size_t base = (size_t)n * 768 + col;
            floatx4 i4 = *reinterpret_cast<const floatx4*>(iou_in + base);
            floatx4 o4 = *reinterpret_cast<const floatx4*>(iou_in + base + 256);
            floatx4 u4 = *reinterpret_cast<const floatx4*>(iou_in + base + 512);
            floatx4 cc, hh;
            #pragma unroll
            for (int r = 0; r < 4; ++r) {
                int t = q * 4 + r;
                float c = sigf(accI[t] + 2.f*i4[r]) * tanhfast(accU[t] + 2.f*u4[r])
                          + cagg[t];
                cc[r] = c;
                hh[r] = sigf(accO[t] + 2.f*o4[r]) * tanhfast(c);
            }
            *reinterpret_cast<floatx4*>(out + (size_t)n * HD + col) = hh;
            *reinterpret_cast<floatx4*>(out + (size_t)(NN + n) * HD + col) = cc;
        }
    }
}

// ===========================================================================
extern "C" void kernel_launch(void* const* d_in, const int* in_sizes, int n_in,
                              void* d_out, int out_size, void* d_ws, size_t ws_size,
                              hipStream_t stream) {
    const float* nh     = (const float*)d_in[0];
    const float* ncc    = (const float*)d_in[1];
    const float* f_in   = (const float*)d_in[2];
    const float* iou_in = (const float*)d_in[3];
    const float* U_f    = (const float*)d_in[4];
    const float* U_iou  = (const float*)d_in[5];
    unsigned short* wsB = (unsigned short*)d_ws;

    const size_t FRAG_BYTES  = (size_t)98304 * 16;   // 1.5 MiB
    const size_t LOGITS_OFF  = (size_t)2 << 20;      // logits region at +2 MiB

    long long cmax = 0;
    if (ws_size > LOGITS_OFF)
        cmax = (long long)((ws_size - LOGITS_OFF) / 3072);
    cmax = (cmax / 128) * 128;

    if (cmax >= 128) {
        // ---------------- split path ----------------
        hipLaunchKernelGGL(prep_split, dim3(384), dim3(256), 0, stream,
                           U_f, U_iou, wsB);
        unsigned short* logits =
            (unsigned short*)((char*)d_ws + LOGITS_OFF);
        int base = 0;
        while (base < NN) {
            long long rem = NN - base;
            int count = (int)(rem < cmax ? rem : cmax);
            int nmb = (count + 127) / 128;
            hipLaunchKernelGGL(gemm_logits, dim3(nmb * 12), dim3(256), 0,
                               stream, nh, wsB, logits, base, count);
            int ewgrid = (count * 64 + 255) / 256;
            if (ewgrid > 2048) ewgrid = 2048;
            hipLaunchKernelGGL(ew_kernel, dim3(ewgrid), dim3(256), 0, stream,
                               logits, ncc, f_in, iou_in, (float*)d_out,
                               base, count);
            base += count;
        }
    } else if (ws_size >= FRAG_BYTES) {
        // ---------------- fused fallback (r8) ----------------
        hipLaunchKernelGGL(prep_fused32, dim3(384), dim3(256), 0, stream,
                           U_f, U_iou, wsB);
        hipLaunchKernelGGL(fused_main, dim3((NN + 31) / 32), dim3(512), 0,
                           stream, nh, ncc, f_in, iou_in, wsB, (float*)d_out);
    }
}

// Round 12
// 309.622 us; speedup vs baseline: 1.3645x; 1.3645x over previous
//
#include <hip/hip_runtime.h>
#include <cstdint>
#include <cstddef>

#define NN 50000
#define HD 256
#define NCH 3

typedef __attribute__((ext_vector_type(8))) short shortx8;
typedef __attribute__((ext_vector_type(4))) float floatx4;
typedef __attribute__((ext_vector_type(16))) float floatx16;

__device__ __forceinline__ unsigned short f2bf(float x) {
    union { float f; uint32_t u; } v; v.f = x;
    uint32_t r = v.u + 0x7fffu + ((v.u >> 16) & 1u);   // RNE
    return (unsigned short)(r >> 16);
}
__device__ __forceinline__ float bf2f(unsigned short u) {
    union { uint32_t u; float f; } v; v.u = ((uint32_t)u) << 16; return v.f;
}
__device__ __forceinline__ uint32_t cvtpk(float a, float b) {
    uint32_t r;
    asm("v_cvt_pk_bf16_f32 %0, %1, %2" : "=v"(r) : "v"(a), "v"(b));
    return r;
}
__device__ __forceinline__ float sigf(float x) {
    return 1.0f / (1.0f + __expf(-x));
}
__device__ __forceinline__ float tanhfast(float x) {
    return 1.0f - 2.0f / (__expf(2.0f * x) + 1.0f);
}
__device__ __forceinline__ floatx16 mfma32(shortx8 a, shortx8 b, floatx16 c) {
    return __builtin_amdgcn_mfma_f32_32x32x16_bf16(a, b, c, 0, 0, 0);
}
// async global->LDS, 16B per lane; LDS dest = uniform base + lane*16
__device__ __forceinline__ void glds16(const void* g, void* l) {
    __builtin_amdgcn_global_load_lds(
        (const __attribute__((address_space(1))) void*)g,
        (__attribute__((address_space(3))) void*)l, 16, 0, 0);
}

// ===========================================================================
// Weight prep (verified r11): W' [768K x 1536 cols] bf16 frags, 32x32x16.
// F tiles t(0..23) x ksl(0..15) at fg = t*16+ksl (K-support d*256..+256);
// IOU tiles t2(0..23) x ksl(0..47) at fg = 384 + t2*48 + ksl.
// frag: wcol = tile*32+(lane&31), k = ksl*16+(lane>>5)*8+e.
// ===========================================================================
__global__ void prep_split(const float* __restrict__ U_f,
                           const float* __restrict__ U_iou,
                           unsigned short* __restrict__ wsB) {
    int idx  = blockIdx.x * 256 + threadIdx.x;   // 98304 total
    int lane = idx & 63;
    int fg   = idx >> 6;
    const float* src;
    if (fg < 384) {
        int t   = fg >> 4;
        int ksl = fg & 15;
        int d   = t >> 3;
        int c   = t * 32 + (lane & 31) - d * 256;
        int kk  = ksl * 16 + (lane >> 5) * 8;
        src = U_f + ((size_t)d * 256 + c) * 256 + kk;
    } else {
        int fg2 = fg - 384;
        int t2  = fg2 / 48;
        int ksl = fg2 % 48;
        int gc  = t2 * 32 + (lane & 31);
        int g   = gc >> 8;
        int c   = gc & 255;
        int k   = ksl * 16 + (lane >> 5) * 8;
        int d   = k >> 8;
        int kk  = k & 255;
        src = U_iou + ((size_t)d * 768 + g * 256 + c) * 256 + kk;
    }
    shortx8 o;
    #pragma unroll
    for (int e = 0; e < 8; ++e) o[e] = (short)f2bf(src[e]);
    reinterpret_cast<shortx8*>(wsB)[idx] = o;
}

// ---------------------------------------------------------------------------
// conv_nh: nh fp32 [base..base+count)x768 -> bf16, chunk-swizzled per 64-k
// slab: dst[r][S*64 + (c ^ (r&7))*8 + e], c = local chunk (k>>3)&7.
// Linear glds staging then yields swizzled LDS; reads use ch^(node&7).
// ---------------------------------------------------------------------------
__global__ __launch_bounds__(256) void conv_nh(
    const float* __restrict__ nh, unsigned short* __restrict__ dst,
    int base, int count)
{
    int total = count * 96;
    for (int id = blockIdx.x * 256 + threadIdx.x; id < total;
         id += gridDim.x * 256) {
        int r = id / 96;
        int q = id - r * 96;
        const float4* s4 = reinterpret_cast<const float4*>(
            nh + (size_t)(base + r) * 768 + q * 8);
        float4 a = s4[0], b = s4[1];
        union { uint32_t u[4]; shortx8 v; } o;
        o.u[0] = cvtpk(a.x, a.y); o.u[1] = cvtpk(a.z, a.w);
        o.u[2] = cvtpk(b.x, b.y); o.u[3] = cvtpk(b.z, b.w);
        int S = q >> 3, c = q & 7;
        *reinterpret_cast<shortx8*>(
            dst + (size_t)r * 768 + S * 64 + ((c ^ (r & 7)) * 8)) = o.v;
    }
}

// ---------------------------------------------------------------------------
// GEMM (m97-style): logits[row][1536] bf16 = nh_swz (K) x W'.
// 256 thr = 4 waves, BM=128 nodes, BN=128 cols (wave cg = 32-col tile),
// BK=64, 32 KiB single-buffered LDS (16K nh + 16K weights), per step:
// stage via 8 glds/wave -> barrier -> 4 A-ds_read(linear) + 16 B-ds_read
// + 16 MFMA -> barrier. F col-blocks (cb<6) K=256; IOU K=768.
// ---------------------------------------------------------------------------
__global__ __launch_bounds__(256, 3) void gemm_logits(
    const unsigned short* __restrict__ nhb,    // [count][768] swizzled bf16
    const unsigned short* __restrict__ wsB,
    unsigned short* __restrict__ logits,       // [count][1536]
    int count)
{
    __shared__ unsigned short nhT[128 * 64];   // 16 KiB
    __shared__ unsigned short wT[16 * 512];    // 16 KiB

    const int tid = threadIdx.x;
    const int bid = blockIdx.x;
    const int cb  = bid % 12;
    const int mb  = bid / 12;
    const int nbl = mb * 128;

    const int lane = tid & 63;
    const int cg   = tid >> 6;
    const int nl   = lane & 31;
    const int hi   = lane >> 5;

    const bool isF   = (cb < 6);
    const int  dch   = cb >> 1;
    const int  kbase = isF ? dch * 256 : 0;      // in shorts
    const int  nsteps = isF ? 4 : 12;
    const int  tF  = cb * 4 + cg;
    const int  t2  = (cb - 6) * 4 + cg;
    const int  fragbase = isF ? (tF * 16) : (384 + t2 * 48);
    const int  colbase  = (isF ? (tF * 32) : (768 + t2 * 32)) + hi * 4;
    const int  clim = count - 1;

    floatx16 acc[4];
    #pragma unroll
    for (int nt = 0; nt < 4; ++nt)
        #pragma unroll
        for (int t = 0; t < 16; ++t) acc[nt][t] = 0.0f;

    for (int s = 0; s < nsteps; ++s) {
        // ---- stage: 4 nh + 4 weight glds per wave ----
        #pragma unroll
        for (int jj = 0; jj < 4; ++jj) {
            int j    = cg * 4 + jj;            // 0..15
            int el   = j * 64 + lane;
            int node = el >> 3;
            int kk8  = (el & 7) * 8;
            int row  = nbl + node; if (row > clim) row = clim;
            glds16(nhb + (size_t)row * 768 + kbase + s * 64 + kk8,
                   (void*)(nhT + j * 512));
        }
        #pragma unroll
        for (int jj = 0; jj < 4; ++jj) {
            int frag = fragbase + s * 4 + jj;
            glds16(wsB + (size_t)frag * 512 + lane * 8,
                   (void*)(wT + (cg * 4 + jj) * 512));
        }
        __syncthreads();   // drains glds (vmcnt0) -> tiles ready

        // ---- compute: 16 MFMAs ----
        #pragma unroll
        for (int it = 0; it < 4; ++it) {
            shortx8 a = *reinterpret_cast<const shortx8*>(
                wT + (cg * 4 + it) * 512 + lane * 8);
            int ch = it * 2 + hi;
            #pragma unroll
            for (int nt = 0; nt < 4; ++nt) {
                int nd = nt * 32 + nl;
                shortx8 b = *reinterpret_cast<const shortx8*>(
                    nhT + nd * 64 + ((ch ^ (nl & 7)) * 8));
                acc[nt] = mfma32(a, b, acc[nt]);
            }
        }
        __syncthreads();   // all reads done before next overwrite
    }

    // ---- epilogue: bf16 logits ----
    #pragma unroll
    for (int nt = 0; nt < 4; ++nt) {
        int row = nbl + nt * 32 + nl;
        if (row < count) {
            unsigned short* lr = logits + (size_t)row * 1536;
            #pragma unroll
            for (int q = 0; q < 4; ++q) {
                uint2 wv;
                wv.x = cvtpk(acc[nt][q * 4 + 0], acc[nt][q * 4 + 1]);
                wv.y = cvtpk(acc[nt][q * 4 + 2], acc[nt][q * 4 + 3]);
                *reinterpret_cast<uint2*>(lr + colbase + q * 8) = wv;
            }
        }
    }
}

// ---------------------------------------------------------------------------
// Elementwise (verified r11, roofline): pure streaming float4.
// ---------------------------------------------------------------------------
__global__ __launch_bounds__(256) void ew_kernel(
    const unsigned short* __restrict__ logits, // [count][1536]
    const float* __restrict__ ncc,
    const float* __restrict__ f_in,
    const float* __restrict__ iou_in,
    float* __restrict__ out,
    int node_base, int count)
{
    int total = count * 64;
    for (int id = blockIdx.x * 256 + threadIdx.x; id < total;
         id += gridDim.x * 256) {
        int row = id >> 6;
        int col = (id & 63) * 4;
        int gn  = node_base + row;
        const unsigned short* lr = logits + (size_t)row * 1536;

        floatx4 fi = *reinterpret_cast<const floatx4*>(
            f_in + (size_t)gn * HD + col);
        float cagg[4] = {0.f, 0.f, 0.f, 0.f};
        #pragma unroll
        for (int d = 0; d < 3; ++d) {
            ushort4 fb = *reinterpret_cast<const ushort4*>(lr + d * 256 + col);
            floatx4 nc4 = *reinterpret_cast<const floatx4*>(
                ncc + (size_t)gn * 768 + d * 256 + col);
            cagg[0] += sigf(bf2f(fb.x) + fi[0]) * nc4[0];
            cagg[1] += sigf(bf2f(fb.y) + fi[1]) * nc4[1];
            cagg[2] += sigf(bf2f(fb.z) + fi[2]) * nc4[2];
            cagg[3] += sigf(bf2f(fb.w) + fi[3]) * nc4[3];
        }
        ushort4 ib = *reinterpret_cast<const ushort4*>(lr +  768 + col);
        ushort4 ob = *reinterpret_cast<const ushort4*>(lr + 1024 + col);
        ushort4 ub = *reinterpret_cast<const ushort4*>(lr + 1280 + col);
        size_t iob = (size_t)gn * 768 + col;
        floatx4 i4 = *reinterpret_cast<const floatx4*>(iou_in + iob);
        floatx4 o4 = *reinterpret_cast<const floatx4*>(iou_in + iob + 256);
        floatx4 u4 = *reinterpret_cast<const floatx4*>(iou_in + iob + 512);
        float iv[4] = {bf2f(ib.x), bf2f(ib.y), bf2f(ib.z), bf2f(ib.w)};
        float ov[4] = {bf2f(ob.x), bf2f(ob.y), bf2f(ob.z), bf2f(ob.w)};
        float uv[4] = {bf2f(ub.x), bf2f(ub.y), bf2f(ub.z), bf2f(ub.w)};
        floatx4 cc, hh;
        #pragma unroll
        for (int r = 0; r < 4; ++r) {
            float c = sigf(iv[r] + 2.0f * i4[r]) * tanhfast(uv[r] + 2.0f * u4[r])
                      + cagg[r];
            cc[r] = c;
            hh[r] = sigf(ov[r] + 2.0f * o4[r]) * tanhfast(c);
        }
        *reinterpret_cast<floatx4*>(out + (size_t)gn * HD + col) = hh;
        *reinterpret_cast<floatx4*>(out + (size_t)(NN + gn) * HD + col) = cc;
    }
}

// ===========================================================================
// FALLBACK (r8 fused, verified): used when ws too small for split.
// ===========================================================================
__global__ void prep_fused32(const float* __restrict__ U_f,
                             const float* __restrict__ U_iou,
                             unsigned short* __restrict__ wsB) {
    int idx = blockIdx.x * 256 + threadIdx.x;
    int lane = idx & 63;
    int ks   = (idx >> 6) & 15;
    int tile = (idx >> 10) & 31;
    int d    = idx >> 15;
    if (d >= NCH) return;
    int col = tile * 32 + (lane & 31);
    int k0  = ks * 16 + (lane >> 5) * 8;
    const float* src = (col < 256)
        ? (U_f   + (((size_t)d * 256 + col)         * 256 + k0))
        : (U_iou + (((size_t)d * 768 + (col - 256)) * 256 + k0));
    shortx8 o;
    #pragma unroll
    for (int e = 0; e < 8; ++e) o[e] = (short)f2bf(src[e]);
    reinterpret_cast<shortx8*>(wsB)[idx] = o;
}

__global__ __launch_bounds__(512, 4) void fused_main(
    const float* __restrict__ nh, const float* __restrict__ ncc,
    const float* __restrict__ f_in, const float* __restrict__ iou_in,
    const unsigned short* __restrict__ wsB, float* __restrict__ out)
{
    __shared__ unsigned short sA[NCH * 32 * 32 * 8];
    const int tid  = threadIdx.x;
    const int nb   = blockIdx.x * 32;
    const int lane = tid & 63;
    const int cg   = tid >> 6;
    const int nl   = lane & 31;
    const int hi   = lane >> 5;
    const int colb = cg * 32 + hi * 4;
    const shortx8* Bfr = reinterpret_cast<const shortx8*>(wsB);
    #pragma unroll
    for (int i = 0; i < 6; ++i) {
        int c = i * 512 + tid;
        int d = c >> 10, node = (c >> 5) & 31, slot = c & 31;
        int gn = nb + node;
        shortx8 o;
        if (gn < NN) {
            const float4* q = reinterpret_cast<const float4*>(
                nh + ((size_t)gn * (NCH * HD) + d * HD + slot * 8));
            float4 a = q[0], b = q[1];
            union { uint32_t u[4]; shortx8 v; } t;
            t.u[0] = cvtpk(a.x, a.y); t.u[1] = cvtpk(a.z, a.w);
            t.u[2] = cvtpk(b.x, b.y); t.u[3] = cvtpk(b.z, b.w);
            o = t.v;
        } else {
            for (int e = 0; e < 8; ++e) o[e] = 0;
        }
        int idx = (d * 32 + node) * 32 + (slot ^ (node & 7));
        *reinterpret_cast<shortx8*>(&sA[idx * 8]) = o;
    }
    __syncthreads();
    const int  n     = nb + nl;
    const bool valid = (n < NN);
    const int  nc_   = valid ? n : (NN - 1);
    ushort4 finb[4];
    #pragma unroll
    for (int q = 0; q < 4; ++q) {
        floatx4 v = *reinterpret_cast<const floatx4*>(
            f_in + (size_t)nc_ * HD + colb + q * 8);
        finb[q] = ushort4{f2bf(v[0]), f2bf(v[1]), f2bf(v[2]), f2bf(v[3])};
    }
    float cagg[16];
    #pragma unroll
    for (int t = 0; t < 16; ++t) cagg[t] = 0.0f;
    floatx16 accI, accO, accU;
    #pragma unroll
    for (int t = 0; t < 16; ++t) { accI[t] = 0.f; accO[t] = 0.f; accU[t] = 0.f; }
    const int nsw = nl & 7;
    #pragma unroll 1
    for (int d = 0; d < NCH; ++d) {
        floatx16 accF;
        #pragma unroll
        for (int t = 0; t < 16; ++t) accF[t] = 0.0f;
        #pragma unroll 2
        for (int ks = 0; ks < 16; ++ks) {
            shortx8 aF = Bfr[((d * 32 +      cg) * 16 + ks) * 64 + lane];
            shortx8 aI = Bfr[((d * 32 +  8 + cg) * 16 + ks) * 64 + lane];
            shortx8 aO = Bfr[((d * 32 + 16 + cg) * 16 + ks) * 64 + lane];
            shortx8 aU = Bfr[((d * 32 + 24 + cg) * 16 + ks) * 64 + lane];
            int ch = (ks * 2 + hi) ^ nsw;
            shortx8 b = *reinterpret_cast<const shortx8*>(
                &sA[((d * 32 + nl) * 32 + ch) * 8]);
            accF = mfma32(aF, b, accF);
            accI = mfma32(aI, b, accI);
            accO = mfma32(aO, b, accO);
            accU = mfma32(aU, b, accU);
        }
        #pragma unroll
        for (int q = 0; q < 4; ++q) {
            floatx4 ncr = *reinterpret_cast<const floatx4*>(
                ncc + (size_t)nc_ * (NCH * HD) + d * HD + colb + q * 8);
            cagg[q*4+0] += sigf(accF[q*4+0] + bf2f(finb[q].x)) * ncr[0];
            cagg[q*4+1] += sigf(accF[q*4+1] + bf2f(finb[q].y)) * ncr[1];
            cagg[q*4+2] += sigf(accF[q*4+2] + bf2f(finb[q].z)) * ncr[2];
            cagg[q*4+3] += sigf(accF[q*4+3] + bf2f(finb[q].w)) * ncr[3];
        }
    }
    if (valid) {
        #pragma unroll
        for (int q = 0; q < 4; ++q) {
            int col = colb + q * 8;
            size_t base = (size_t)n * 768 + col;
            floatx4 i4 = *reinterpret_cast<const floatx4*>(iou_in + base);
            floatx4 o4 = *reinterpret_cast<const floatx4*>(iou_in + base + 256);
            floatx4 u4 = *reinterpret_cast<const floatx4*>(iou_in + base + 512);
            floatx4 cc, hh;
            #pragma unroll
            for (int r = 0; r < 4; ++r) {
                int t = q * 4 + r;
                float c = sigf(accI[t] + 2.f*i4[r]) * tanhfast(accU[t] + 2.f*u4[r])
                          + cagg[t];
                cc[r] = c;
                hh[r] = sigf(accO[t] + 2.f*o4[r]) * tanhfast(c);
            }
            *reinterpret_cast<floatx4*>(out + (size_t)n * HD + col) = hh;
            *reinterpret_cast<floatx4*>(out + (size_t)(NN + n) * HD + col) = cc;
        }
    }
}

// ===========================================================================
extern "C" void kernel_launch(void* const* d_in, const int* in_sizes, int n_in,
                              void* d_out, int out_size, void* d_ws, size_t ws_size,
                              hipStream_t stream) {
    const float* nh     = (const float*)d_in[0];
    const float* ncc    = (const float*)d_in[1];
    const float* f_in   = (const float*)d_in[2];
    const float* iou_in = (const float*)d_in[3];
    const float* U_f    = (const float*)d_in[4];
    const float* U_iou  = (const float*)d_in[5];
    unsigned short* wsB = (unsigned short*)d_ws;

    const size_t FRAG_BYTES = (size_t)98304 * 16;    // 1.5 MiB
    const size_t DATA_OFF   = (size_t)2 << 20;       // per-chunk data at +2 MiB

    long long cmax = 0;
    if (ws_size > DATA_OFF)
        cmax = (long long)((ws_size - DATA_OFF) / 4608);   // 1536B nh + 3072B logits
    cmax = (cmax / 128) * 128;

    if (cmax >= 128) {
        hipLaunchKernelGGL(prep_split, dim3(384), dim3(256), 0, stream,
                           U_f, U_iou, wsB);
        unsigned short* nhswz  = (unsigned short*)((char*)d_ws + DATA_OFF);
        unsigned short* logits = nhswz + (size_t)cmax * 768;
        int base = 0;
        while (base < NN) {
            long long rem = NN - base;
            int count = (int)(rem < cmax ? rem : cmax);

            int cgrid = (count * 96 + 255) / 256;
            if (cgrid > 2048) cgrid = 2048;
            hipLaunchKernelGGL(conv_nh, dim3(cgrid), dim3(256), 0, stream,
                               nh, nhswz, base, count);

            int nmb = (count + 127) / 128;
            hipLaunchKernelGGL(gemm_logits, dim3(nmb * 12), dim3(256), 0,
                               stream, nhswz, wsB, logits, count);

            int ewgrid = (count * 64 + 255) / 256;
            if (ewgrid > 2048) ewgrid = 2048;
            hipLaunchKernelGGL(ew_kernel, dim3(ewgrid), dim3(256), 0, stream,
                               logits, ncc, f_in, iou_in, (float*)d_out,
                               base, count);
            base += count;
        }
    } else if (ws_size >= FRAG_BYTES) {
        hipLaunchKernelGGL(prep_fused32, dim3(384), dim3(256), 0, stream,
                           U_f, U_iou, wsB);
        hipLaunchKernelGGL(fused_main, dim3((NN + 31) / 32), dim3(512), 0,
                           stream, nh, ncc, f_in, iou_in, wsB, (float*)d_out);
    }
}

// Round 13
// 303.921 us; speedup vs baseline: 1.3901x; 1.0188x over previous
//
#include <hip/hip_runtime.h>
#include <cstdint>
#include <cstddef>

#define NN 50000
#define HD 256
#define NCH 3

typedef __attribute__((ext_vector_type(8))) short shortx8;
typedef __attribute__((ext_vector_type(4))) float floatx4;
typedef __attribute__((ext_vector_type(16))) float floatx16;

__device__ __forceinline__ unsigned short f2bf(float x) {
    union { float f; uint32_t u; } v; v.f = x;
    uint32_t r = v.u + 0x7fffu + ((v.u >> 16) & 1u);   // RNE
    return (unsigned short)(r >> 16);
}
__device__ __forceinline__ float bf2f(unsigned short u) {
    union { uint32_t u; float f; } v; v.u = ((uint32_t)u) << 16; return v.f;
}
__device__ __forceinline__ uint32_t cvtpk(float a, float b) {
    uint32_t r;
    asm("v_cvt_pk_bf16_f32 %0, %1, %2" : "=v"(r) : "v"(a), "v"(b));
    return r;
}
__device__ __forceinline__ float sigf(float x) {
    return 1.0f / (1.0f + __expf(-x));
}
__device__ __forceinline__ float tanhfast(float x) {
    return 1.0f - 2.0f / (__expf(2.0f * x) + 1.0f);
}
__device__ __forceinline__ floatx16 mfma32(shortx8 a, shortx8 b, floatx16 c) {
    return __builtin_amdgcn_mfma_f32_32x32x16_bf16(a, b, c, 0, 0, 0);
}
// async global->LDS, 16B per lane; LDS dest = wave-uniform base + lane*16
__device__ __forceinline__ void glds16(const void* g, void* l) {
    __builtin_amdgcn_global_load_lds(
        (const __attribute__((address_space(1))) void*)g,
        (__attribute__((address_space(3))) void*)l, 16, 0, 0);
}

// ===========================================================================
// Weight prep (verified): W' bf16 frags, 32x32x16.
// F tiles t(0..23) x ksl(0..15) at fg = t*16+ksl (K-support d=t>>3);
// IOU tiles t2(0..23) x ksl(0..47) at fg = 384 + t2*48 + ksl.
// frag: wcol = tile*32+(lane&31), k = ksl*16+(lane>>5)*8+e.
// ===========================================================================
__global__ void prep_split(const float* __restrict__ U_f,
                           const float* __restrict__ U_iou,
                           unsigned short* __restrict__ wsB) {
    int idx  = blockIdx.x * 256 + threadIdx.x;   // 98304 total
    int lane = idx & 63;
    int fg   = idx >> 6;
    const float* src;
    if (fg < 384) {
        int t   = fg >> 4;
        int ksl = fg & 15;
        int d   = t >> 3;
        int c   = t * 32 + (lane & 31) - d * 256;
        int kk  = ksl * 16 + (lane >> 5) * 8;
        src = U_f + ((size_t)d * 256 + c) * 256 + kk;
    } else {
        int fg2 = fg - 384;
        int t2  = fg2 / 48;
        int ksl = fg2 % 48;
        int gc  = t2 * 32 + (lane & 31);
        int g   = gc >> 8;
        int c   = gc & 255;
        int k   = ksl * 16 + (lane >> 5) * 8;
        int d   = k >> 8;
        int kk  = k & 255;
        src = U_iou + ((size_t)d * 768 + g * 256 + c) * 256 + kk;
    }
    shortx8 o;
    #pragma unroll
    for (int e = 0; e < 8; ++e) o[e] = (short)f2bf(src[e]);
    reinterpret_cast<shortx8*>(wsB)[idx] = o;
}

// ---------------------------------------------------------------------------
// conv_nh (verified): nh fp32 -> bf16, chunk-swizzled per 64-k slab:
// dst[r][S*64 + (c ^ (r&7))*8 + e].
// ---------------------------------------------------------------------------
__global__ __launch_bounds__(256) void conv_nh(
    const float* __restrict__ nh, unsigned short* __restrict__ dst,
    int base, int count)
{
    int total = count * 96;
    for (int id = blockIdx.x * 256 + threadIdx.x; id < total;
         id += gridDim.x * 256) {
        int r = id / 96;
        int q = id - r * 96;
        const float4* s4 = reinterpret_cast<const float4*>(
            nh + (size_t)(base + r) * 768 + q * 8);
        float4 a = s4[0], b = s4[1];
        union { uint32_t u[4]; shortx8 v; } o;
        o.u[0] = cvtpk(a.x, a.y); o.u[1] = cvtpk(a.z, a.w);
        o.u[2] = cvtpk(b.x, b.y); o.u[3] = cvtpk(b.z, b.w);
        int S = q >> 3, c = q & 7;
        *reinterpret_cast<shortx8*>(
            dst + (size_t)r * 768 + S * 64 + ((c ^ (r & 7)) * 8)) = o.v;
    }
}

// ---------------------------------------------------------------------------
// GEMM (m97-style, widened): 512 thr = 8 waves, BM=128 nodes, BN=256 cols
// (wave cg = one 32-col tile), BK=64. cb 0..2: F child d=cb (K=256, 4 steps);
// cb 3..5: IOU (K=768, 12 steps). Per step: 2 nh glds + 4 weight glds per
// thread -> barrier -> 4 A + 16 B ds_reads + 16 MFMA -> barrier.
// LDS 48 KiB single-buffered; acc 64 f/thread; 2 blocks/CU = 16 waves (50%).
// ---------------------------------------------------------------------------
__global__ __launch_bounds__(512, 4) void gemm_logits(
    const unsigned short* __restrict__ nhb,    // [count][768] swizzled bf16
    const unsigned short* __restrict__ wsB,
    unsigned short* __restrict__ logits,       // [count][1536]
    int count)
{
    __shared__ unsigned short nhT[128 * 64];   // 16 KiB
    __shared__ unsigned short wT[32 * 512];    // 32 KiB

    const int tid = threadIdx.x;
    const int bid = blockIdx.x;
    const int cb  = bid % 6;
    const int mb  = bid / 6;
    const int nbl = mb * 128;

    const int lane = tid & 63;
    const int cg   = tid >> 6;        // wave 0..7 = col tile
    const int nl   = lane & 31;
    const int hi   = lane >> 5;

    const bool isF    = (cb < 3);
    const int  kbase  = isF ? cb * 256 : 0;       // in shorts
    const int  nsteps = isF ? 4 : 12;
    const int  tF  = cb * 8 + cg;                 // F tile 0..23
    const int  t2  = (cb - 3) * 8 + cg;           // IOU tile 0..23
    const int  fragbase = isF ? (tF * 16) : (384 + t2 * 48);
    const int  colbase  = (isF ? (tF * 32) : (768 + t2 * 32)) + hi * 4;
    const int  clim = count - 1;

    floatx16 acc[4];
    #pragma unroll
    for (int nt = 0; nt < 4; ++nt)
        #pragma unroll
        for (int t = 0; t < 16; ++t) acc[nt][t] = 0.0f;

    for (int s = 0; s < nsteps; ++s) {
        // ---- stage: 2 nh + 4 weight glds per thread ----
        #pragma unroll
        for (int jj = 0; jj < 2; ++jj) {
            int j    = cg * 2 + jj;            // 0..15 (8 nodes each)
            int el   = j * 64 + lane;
            int node = el >> 3;
            int kk8  = (el & 7) * 8;
            int row  = nbl + node; if (row > clim) row = clim;
            glds16(nhb + (size_t)row * 768 + kbase + s * 64 + kk8,
                   (void*)(nhT + j * 512));
        }
        #pragma unroll
        for (int jj = 0; jj < 4; ++jj) {
            int frag = fragbase + s * 4 + jj;
            glds16(wsB + (size_t)frag * 512 + lane * 8,
                   (void*)(wT + (cg * 4 + jj) * 512));
        }
        __syncthreads();   // drains glds -> tiles ready

        // ---- compute: 16 MFMAs ----
        #pragma unroll
        for (int it = 0; it < 4; ++it) {
            shortx8 a = *reinterpret_cast<const shortx8*>(
                wT + (cg * 4 + it) * 512 + lane * 8);
            int ch = it * 2 + hi;
            #pragma unroll
            for (int nt = 0; nt < 4; ++nt) {
                int nd = nt * 32 + nl;
                shortx8 b = *reinterpret_cast<const shortx8*>(
                    nhT + nd * 64 + ((ch ^ (nl & 7)) * 8));
                acc[nt] = mfma32(a, b, acc[nt]);
            }
        }
        __syncthreads();   // reads done before next overwrite
    }

    // ---- epilogue: bf16 logits ----
    #pragma unroll
    for (int nt = 0; nt < 4; ++nt) {
        int row = nbl + nt * 32 + nl;
        if (row < count) {
            unsigned short* lr = logits + (size_t)row * 1536;
            #pragma unroll
            for (int q = 0; q < 4; ++q) {
                uint2 wv;
                wv.x = cvtpk(acc[nt][q * 4 + 0], acc[nt][q * 4 + 1]);
                wv.y = cvtpk(acc[nt][q * 4 + 2], acc[nt][q * 4 + 3]);
                *reinterpret_cast<uint2*>(lr + colbase + q * 8) = wv;
            }
        }
    }
}

// ---------------------------------------------------------------------------
// Elementwise (verified, roofline): pure streaming float4.
// ---------------------------------------------------------------------------
__global__ __launch_bounds__(256) void ew_kernel(
    const unsigned short* __restrict__ logits, // [count][1536]
    const float* __restrict__ ncc,
    const float* __restrict__ f_in,
    const float* __restrict__ iou_in,
    float* __restrict__ out,
    int node_base, int count)
{
    int total = count * 64;
    for (int id = blockIdx.x * 256 + threadIdx.x; id < total;
         id += gridDim.x * 256) {
        int row = id >> 6;
        int col = (id & 63) * 4;
        int gn  = node_base + row;
        const unsigned short* lr = logits + (size_t)row * 1536;

        floatx4 fi = *reinterpret_cast<const floatx4*>(
            f_in + (size_t)gn * HD + col);
        float cagg[4] = {0.f, 0.f, 0.f, 0.f};
        #pragma unroll
        for (int d = 0; d < 3; ++d) {
            ushort4 fb = *reinterpret_cast<const ushort4*>(lr + d * 256 + col);
            floatx4 nc4 = *reinterpret_cast<const floatx4*>(
                ncc + (size_t)gn * 768 + d * 256 + col);
            cagg[0] += sigf(bf2f(fb.x) + fi[0]) * nc4[0];
            cagg[1] += sigf(bf2f(fb.y) + fi[1]) * nc4[1];
            cagg[2] += sigf(bf2f(fb.z) + fi[2]) * nc4[2];
            cagg[3] += sigf(bf2f(fb.w) + fi[3]) * nc4[3];
        }
        ushort4 ib = *reinterpret_cast<const ushort4*>(lr +  768 + col);
        ushort4 ob = *reinterpret_cast<const ushort4*>(lr + 1024 + col);
        ushort4 ub = *reinterpret_cast<const ushort4*>(lr + 1280 + col);
        size_t iob = (size_t)gn * 768 + col;
        floatx4 i4 = *reinterpret_cast<const floatx4*>(iou_in + iob);
        floatx4 o4 = *reinterpret_cast<const floatx4*>(iou_in + iob + 256);
        floatx4 u4 = *reinterpret_cast<const floatx4*>(iou_in + iob + 512);
        float iv[4] = {bf2f(ib.x), bf2f(ib.y), bf2f(ib.z), bf2f(ib.w)};
        float ov[4] = {bf2f(ob.x), bf2f(ob.y), bf2f(ob.z), bf2f(ob.w)};
        float uv[4] = {bf2f(ub.x), bf2f(ub.y), bf2f(ub.z), bf2f(ub.w)};
        floatx4 cc, hh;
        #pragma unroll
        for (int r = 0; r < 4; ++r) {
            float c = sigf(iv[r] + 2.0f * i4[r]) * tanhfast(uv[r] + 2.0f * u4[r])
                      + cagg[r];
            cc[r] = c;
            hh[r] = sigf(ov[r] + 2.0f * o4[r]) * tanhfast(c);
        }
        *reinterpret_cast<floatx4*>(out + (size_t)gn * HD + col) = hh;
        *reinterpret_cast<floatx4*>(out + (size_t)(NN + gn) * HD + col) = cc;
    }
}

// ===========================================================================
// FALLBACK (r8 fused, verified): used when ws too small for split.
// ===========================================================================
__global__ void prep_fused32(const float* __restrict__ U_f,
                             const float* __restrict__ U_iou,
                             unsigned short* __restrict__ wsB) {
    int idx = blockIdx.x * 256 + threadIdx.x;
    int lane = idx & 63;
    int ks   = (idx >> 6) & 15;
    int tile = (idx >> 10) & 31;
    int d    = idx >> 15;
    if (d >= NCH) return;
    int col = tile * 32 + (lane & 31);
    int k0  = ks * 16 + (lane >> 5) * 8;
    const float* src = (col < 256)
        ? (U_f   + (((size_t)d * 256 + col)         * 256 + k0))
        : (U_iou + (((size_t)d * 768 + (col - 256)) * 256 + k0));
    shortx8 o;
    #pragma unroll
    for (int e = 0; e < 8; ++e) o[e] = (short)f2bf(src[e]);
    reinterpret_cast<shortx8*>(wsB)[idx] = o;
}

__global__ __launch_bounds__(512, 4) void fused_main(
    const float* __restrict__ nh, const float* __restrict__ ncc,
    const float* __restrict__ f_in, const float* __restrict__ iou_in,
    const unsigned short* __restrict__ wsB, float* __restrict__ out)
{
    __shared__ unsigned short sA[NCH * 32 * 32 * 8];
    const int tid  = threadIdx.x;
    const int nb   = blockIdx.x * 32;
    const int lane = tid & 63;
    const int cg   = tid >> 6;
    const int nl   = lane & 31;
    const int hi   = lane >> 5;
    const int colb = cg * 32 + hi * 4;
    const shortx8* Bfr = reinterpret_cast<const shortx8*>(wsB);
    #pragma unroll
    for (int i = 0; i < 6; ++i) {
        int c = i * 512 + tid;
        int d = c >> 10, node = (c >> 5) & 31, slot = c & 31;
        int gn = nb + node;
        shortx8 o;
        if (gn < NN) {
            const float4* q = reinterpret_cast<const float4*>(
                nh + ((size_t)gn * (NCH * HD) + d * HD + slot * 8));
            float4 a = q[0], b = q[1];
            union { uint32_t u[4]; shortx8 v; } t;
            t.u[0] = cvtpk(a.x, a.y); t.u[1] = cvtpk(a.z, a.w);
            t.u[2] = cvtpk(b.x, b.y); t.u[3] = cvtpk(b.z, b.w);
            o = t.v;
        } else {
            for (int e = 0; e < 8; ++e) o[e] = 0;
        }
        int idx = (d * 32 + node) * 32 + (slot ^ (node & 7));
        *reinterpret_cast<shortx8*>(&sA[idx * 8]) = o;
    }
    __syncthreads();
    const int  n     = nb + nl;
    const bool valid = (n < NN);
    const int  nc_   = valid ? n : (NN - 1);
    ushort4 finb[4];
    #pragma unroll
    for (int q = 0; q < 4; ++q) {
        floatx4 v = *reinterpret_cast<const floatx4*>(
            f_in + (size_t)nc_ * HD + colb + q * 8);
        finb[q] = ushort4{f2bf(v[0]), f2bf(v[1]), f2bf(v[2]), f2bf(v[3])};
    }
    float cagg[16];
    #pragma unroll
    for (int t = 0; t < 16; ++t) cagg[t] = 0.0f;
    floatx16 accI, accO, accU;
    #pragma unroll
    for (int t = 0; t < 16; ++t) { accI[t] = 0.f; accO[t] = 0.f; accU[t] = 0.f; }
    const int nsw = nl & 7;
    #pragma unroll 1
    for (int d = 0; d < NCH; ++d) {
        floatx16 accF;
        #pragma unroll
        for (int t = 0; t < 16; ++t) accF[t] = 0.0f;
        #pragma unroll 2
        for (int ks = 0; ks < 16; ++ks) {
            shortx8 aF = Bfr[((d * 32 +      cg) * 16 + ks) * 64 + lane];
            shortx8 aI = Bfr[((d * 32 +  8 + cg) * 16 + ks) * 64 + lane];
            shortx8 aO = Bfr[((d * 32 + 16 + cg) * 16 + ks) * 64 + lane];
            shortx8 aU = Bfr[((d * 32 + 24 + cg) * 16 + ks) * 64 + lane];
            int ch = (ks * 2 + hi) ^ nsw;
            shortx8 b = *reinterpret_cast<const shortx8*>(
                &sA[((d * 32 + nl) * 32 + ch) * 8]);
            accF = mfma32(aF, b, accF);
            accI = mfma32(aI, b, accI);
            accO = mfma32(aO, b, accO);
            accU = mfma32(aU, b, accU);
        }
        #pragma unroll
        for (int q = 0; q < 4; ++q) {
            floatx4 ncr = *reinterpret_cast<const floatx4*>(
                ncc + (size_t)nc_ * (NCH * HD) + d * HD + colb + q * 8);
            cagg[q*4+0] += sigf(accF[q*4+0] + bf2f(finb[q].x)) * ncr[0];
            cagg[q*4+1] += sigf(accF[q*4+1] + bf2f(finb[q].y)) * ncr[1];
            cagg[q*4+2] += sigf(accF[q*4+2] + bf2f(finb[q].z)) * ncr[2];
            cagg[q*4+3] += sigf(accF[q*4+3] + bf2f(finb[q].w)) * ncr[3];
        }
    }
    if (valid) {
        #pragma unroll
        for (int q = 0; q < 4; ++q) {
            int col = colb + q * 8;
            size_t base = (size_t)n * 768 + col;
            floatx4 i4 = *reinterpret_cast<const floatx4*>(iou_in + base);
            floatx4 o4 = *reinterpret_cast<const floatx4*>(iou_in + base + 256);
            floatx4 u4 = *reinterpret_cast<const floatx4*>(iou_in + base + 512);
            floatx4 cc, hh;
            #pragma unroll
            for (int r = 0; r < 4; ++r) {
                int t = q * 4 + r;
                float c = sigf(accI[t] + 2.f*i4[r]) * tanhfast(accU[t] + 2.f*u4[r])
                          + cagg[t];
                cc[r] = c;
                hh[r] = sigf(accO[t] + 2.f*o4[r]) * tanhfast(c);
            }
            *reinterpret_cast<floatx4*>(out + (size_t)n * HD + col) = hh;
            *reinterpret_cast<floatx4*>(out + (size_t)(NN + n) * HD + col) = cc;
        }
    }
}

// ===========================================================================
extern "C" void kernel_launch(void* const* d_in, const int* in_sizes, int n_in,
                              void* d_out, int out_size, void* d_ws, size_t ws_size,
                              hipStream_t stream) {
    const float* nh     = (const float*)d_in[0];
    const float* ncc    = (const float*)d_in[1];
    const float* f_in   = (const float*)d_in[2];
    const float* iou_in = (const float*)d_in[3];
    const float* U_f    = (const float*)d_in[4];
    const float* U_iou  = (const float*)d_in[5];
    unsigned short* wsB = (unsigned short*)d_ws;

    const size_t FRAG_BYTES = (size_t)98304 * 16;    // 1.5 MiB
    const size_t DATA_OFF   = (size_t)2 << 20;       // per-chunk data at +2 MiB

    long long cmax = 0;
    if (ws_size > DATA_OFF)
        cmax = (long long)((ws_size - DATA_OFF) / 4608);   // 1536B nh + 3072B logits
    cmax = (cmax / 128) * 128;

    if (cmax >= 128) {
        hipLaunchKernelGGL(prep_split, dim3(384), dim3(256), 0, stream,
                           U_f, U_iou, wsB);
        unsigned short* nhswz  = (unsigned short*)((char*)d_ws + DATA_OFF);
        unsigned short* logits = nhswz + (size_t)cmax * 768;
        int base = 0;
        while (base < NN) {
            long long rem = NN - base;
            int count = (int)(rem < cmax ? rem : cmax);

            int cgrid = (count * 96 + 255) / 256;
            if (cgrid > 2048) cgrid = 2048;
            hipLaunchKernelGGL(conv_nh, dim3(cgrid), dim3(256), 0, stream,
                               nh, nhswz, base, count);

            int nmb = (count + 127) / 128;
            hipLaunchKernelGGL(gemm_logits, dim3(nmb * 6), dim3(512), 0,
                               stream, nhswz, wsB, logits, count);

            int ewgrid = (count * 64 + 255) / 256;
            if (ewgrid > 2048) ewgrid = 2048;
            hipLaunchKernelGGL(ew_kernel, dim3(ewgrid), dim3(256), 0, stream,
                               logits, ncc, f_in, iou_in, (float*)d_out,
                               base, count);
            base += count;
        }
    } else if (ws_size >= FRAG_BYTES) {
        hipLaunchKernelGGL(prep_fused32, dim3(384), dim3(256), 0, stream,
                           U_f, U_iou, wsB);
        hipLaunchKernelGGL(fused_main, dim3((NN + 31) / 32), dim3(512), 0,
                           stream, nh, ncc, f_in, iou_in, wsB, (float*)d_out);
    }
}

// Round 14
// 302.106 us; speedup vs baseline: 1.3984x; 1.0060x over previous
//
#include <hip/hip_runtime.h>
#include <cstdint>
#include <cstddef>

#define NN 50000
#define HD 256
#define NCH 3

typedef __attribute__((ext_vector_type(8))) short shortx8;
typedef __attribute__((ext_vector_type(4))) float floatx4;
typedef __attribute__((ext_vector_type(16))) float floatx16;

__device__ __forceinline__ unsigned short f2bf(float x) {
    union { float f; uint32_t u; } v; v.f = x;
    uint32_t r = v.u + 0x7fffu + ((v.u >> 16) & 1u);   // RNE
    return (unsigned short)(r >> 16);
}
__device__ __forceinline__ float bf2f(unsigned short u) {
    union { uint32_t u; float f; } v; v.u = ((uint32_t)u) << 16; return v.f;
}
__device__ __forceinline__ uint32_t cvtpk(float a, float b) {
    uint32_t r;
    asm("v_cvt_pk_bf16_f32 %0, %1, %2" : "=v"(r) : "v"(a), "v"(b));
    return r;
}
__device__ __forceinline__ float sigf(float x) {
    return 1.0f / (1.0f + __expf(-x));
}
__device__ __forceinline__ float tanhfast(float x) {
    return 1.0f - 2.0f / (__expf(2.0f * x) + 1.0f);
}
__device__ __forceinline__ floatx16 mfma32(shortx8 a, shortx8 b, floatx16 c) {
    return __builtin_amdgcn_mfma_f32_32x32x16_bf16(a, b, c, 0, 0, 0);
}
// async global->LDS, 16B per lane; LDS dest = wave-uniform base + lane*16
__device__ __forceinline__ void glds16(const void* g, void* l) {
    __builtin_amdgcn_global_load_lds(
        (const __attribute__((address_space(1))) void*)g,
        (__attribute__((address_space(3))) void*)l, 16, 0, 0);
}

// ===========================================================================
// Weight prep (verified): W' bf16 frags, 32x32x16.
// F tiles t(0..23) x ksl(0..15) at fg = t*16+ksl (K-support d=t>>3);
// IOU tiles t2(0..23) x ksl(0..47) at fg = 384 + t2*48 + ksl.
// frag: wcol = tile*32+(lane&31), k = ksl*16+(lane>>5)*8+e.
// Per-lane 16B at fg*1024 + lane*16 IS the A-operand -> register loads.
// ===========================================================================
__global__ void prep_split(const float* __restrict__ U_f,
                           const float* __restrict__ U_iou,
                           unsigned short* __restrict__ wsB) {
    int idx  = blockIdx.x * 256 + threadIdx.x;   // 98304 total
    int lane = idx & 63;
    int fg   = idx >> 6;
    const float* src;
    if (fg < 384) {
        int t   = fg >> 4;
        int ksl = fg & 15;
        int d   = t >> 3;
        int c   = t * 32 + (lane & 31) - d * 256;
        int kk  = ksl * 16 + (lane >> 5) * 8;
        src = U_f + ((size_t)d * 256 + c) * 256 + kk;
    } else {
        int fg2 = fg - 384;
        int t2  = fg2 / 48;
        int ksl = fg2 % 48;
        int gc  = t2 * 32 + (lane & 31);
        int g   = gc >> 8;
        int c   = gc & 255;
        int k   = ksl * 16 + (lane >> 5) * 8;
        int d   = k >> 8;
        int kk  = k & 255;
        src = U_iou + ((size_t)d * 768 + g * 256 + c) * 256 + kk;
    }
    shortx8 o;
    #pragma unroll
    for (int e = 0; e < 8; ++e) o[e] = (short)f2bf(src[e]);
    reinterpret_cast<shortx8*>(wsB)[idx] = o;
}

// ---------------------------------------------------------------------------
// conv_nh (verified): nh fp32 -> bf16, chunk-swizzled per 64-k slab:
// dst[r][S*64 + (c ^ (r&7))*8 + e].
// ---------------------------------------------------------------------------
__global__ __launch_bounds__(256) void conv_nh(
    const float* __restrict__ nh, unsigned short* __restrict__ dst,
    int base, int count)
{
    int total = count * 96;
    for (int id = blockIdx.x * 256 + threadIdx.x; id < total;
         id += gridDim.x * 256) {
        int r = id / 96;
        int q = id - r * 96;
        const float4* s4 = reinterpret_cast<const float4*>(
            nh + (size_t)(base + r) * 768 + q * 8);
        float4 a = s4[0], b = s4[1];
        union { uint32_t u[4]; shortx8 v; } o;
        o.u[0] = cvtpk(a.x, a.y); o.u[1] = cvtpk(a.z, a.w);
        o.u[2] = cvtpk(b.x, b.y); o.u[3] = cvtpk(b.z, b.w);
        int S = q >> 3, c = q & 7;
        *reinterpret_cast<shortx8*>(
            dst + (size_t)r * 768 + S * 64 + ((c ^ (r & 7)) * 8)) = o.v;
    }
}

// ---------------------------------------------------------------------------
// GEMM (r13 + reg-weights + nh double-buffer): 512 thr = 8 waves, BM=128,
// BN=256 (wave cg = 32-col tile), BK=64. cb 0..2: F child (K=256);
// cb 3..5: IOU (K=768). Per step: issue glds nh(s+1) into other buf +
// global_load w(s+1) regs -> 16 MFMA on buf[s&1]/wcur -> ONE barrier
// (drains all loads). Weights never touch LDS (per-lane 16B = A-operand).
// LDS 32 KiB; acc 64 + w 32 regs -> ~110/thread, 2 blocks/CU.
// ---------------------------------------------------------------------------
__global__ __launch_bounds__(512, 4) void gemm_logits(
    const unsigned short* __restrict__ nhb,    // [count][768] swizzled bf16
    const unsigned short* __restrict__ wsB,
    unsigned short* __restrict__ logits,       // [count][1536]
    int count)
{
    __shared__ unsigned short nhT[2][128 * 64];   // 2 x 16 KiB

    const int tid = threadIdx.x;
    const int bid = blockIdx.x;
    const int cb  = bid % 6;
    const int mb  = bid / 6;
    const int nbl = mb * 128;

    const int lane = tid & 63;
    const int cg   = tid >> 6;        // wave 0..7 = col tile
    const int nl   = lane & 31;
    const int hi   = lane >> 5;

    const bool isF    = (cb < 3);
    const int  kbase  = isF ? cb * 256 : 0;       // in shorts
    const int  nsteps = isF ? 4 : 12;
    const int  tF  = cb * 8 + cg;
    const int  t2  = (cb - 3) * 8 + cg;
    const int  fragbase = isF ? (tF * 16) : (384 + t2 * 48);
    const int  colbase  = (isF ? (tF * 32) : (768 + t2 * 32)) + hi * 4;
    const int  clim = count - 1;

    floatx16 acc[4];
    #pragma unroll
    for (int nt = 0; nt < 4; ++nt)
        #pragma unroll
        for (int t = 0; t < 16; ++t) acc[nt][t] = 0.0f;

#define STAGE_NH(S, B)                                                       \
    {                                                                        \
        _Pragma("unroll")                                                    \
        for (int jj = 0; jj < 2; ++jj) {                                     \
            int j    = cg * 2 + jj;                                          \
            int el   = j * 64 + lane;                                        \
            int node = el >> 3;                                               \
            int kk8  = (el & 7) * 8;                                          \
            int row  = nbl + node; if (row > clim) row = clim;               \
            glds16(nhb + (size_t)row * 768 + kbase + (S) * 64 + kk8,         \
                   (void*)(nhT[(B)] + j * 512));                             \
        }                                                                    \
    }

    shortx8 wcur[4], wnxt[4];
    STAGE_NH(0, 0);
    #pragma unroll
    for (int jj = 0; jj < 4; ++jj)
        wcur[jj] = *reinterpret_cast<const shortx8*>(
            wsB + (size_t)(fragbase + jj) * 512 + lane * 8);
    __syncthreads();   // drains step-0 loads

    for (int s = 0; s < nsteps; ++s) {
        // ---- prefetch step s+1 (overlaps the MFMAs below) ----
        if (s + 1 < nsteps) {
            STAGE_NH(s + 1, (s + 1) & 1);
            #pragma unroll
            for (int jj = 0; jj < 4; ++jj)
                wnxt[jj] = *reinterpret_cast<const shortx8*>(
                    wsB + (size_t)(fragbase + (s + 1) * 4 + jj) * 512 + lane * 8);
        }

        // ---- compute: 16 MFMAs (regs + already-resident LDS) ----
        const unsigned short* buf = nhT[s & 1];
        #pragma unroll
        for (int it = 0; it < 4; ++it) {
            shortx8 a = wcur[it];
            int ch = it * 2 + hi;
            #pragma unroll
            for (int nt = 0; nt < 4; ++nt) {
                int nd = nt * 32 + nl;
                shortx8 b = *reinterpret_cast<const shortx8*>(
                    buf + nd * 64 + ((ch ^ (nl & 7)) * 8));
                acc[nt] = mfma32(a, b, acc[nt]);
            }
        }
        __syncthreads();   // drains s+1 loads; all buf reads done
        #pragma unroll
        for (int jj = 0; jj < 4; ++jj) wcur[jj] = wnxt[jj];
    }
#undef STAGE_NH

    // ---- epilogue: bf16 logits ----
    #pragma unroll
    for (int nt = 0; nt < 4; ++nt) {
        int row = nbl + nt * 32 + nl;
        if (row < count) {
            unsigned short* lr = logits + (size_t)row * 1536;
            #pragma unroll
            for (int q = 0; q < 4; ++q) {
                uint2 wv;
                wv.x = cvtpk(acc[nt][q * 4 + 0], acc[nt][q * 4 + 1]);
                wv.y = cvtpk(acc[nt][q * 4 + 2], acc[nt][q * 4 + 3]);
                *reinterpret_cast<uint2*>(lr + colbase + q * 8) = wv;
            }
        }
    }
}

// ---------------------------------------------------------------------------
// Elementwise (verified, roofline): pure streaming float4.
// ---------------------------------------------------------------------------
__global__ __launch_bounds__(256) void ew_kernel(
    const unsigned short* __restrict__ logits, // [count][1536]
    const float* __restrict__ ncc,
    const float* __restrict__ f_in,
    const float* __restrict__ iou_in,
    float* __restrict__ out,
    int node_base, int count)
{
    int total = count * 64;
    for (int id = blockIdx.x * 256 + threadIdx.x; id < total;
         id += gridDim.x * 256) {
        int row = id >> 6;
        int col = (id & 63) * 4;
        int gn  = node_base + row;
        const unsigned short* lr = logits + (size_t)row * 1536;

        floatx4 fi = *reinterpret_cast<const floatx4*>(
            f_in + (size_t)gn * HD + col);
        float cagg[4] = {0.f, 0.f, 0.f, 0.f};
        #pragma unroll
        for (int d = 0; d < 3; ++d) {
            ushort4 fb = *reinterpret_cast<const ushort4*>(lr + d * 256 + col);
            floatx4 nc4 = *reinterpret_cast<const floatx4*>(
                ncc + (size_t)gn * 768 + d * 256 + col);
            cagg[0] += sigf(bf2f(fb.x) + fi[0]) * nc4[0];
            cagg[1] += sigf(bf2f(fb.y) + fi[1]) * nc4[1];
            cagg[2] += sigf(bf2f(fb.z) + fi[2]) * nc4[2];
            cagg[3] += sigf(bf2f(fb.w) + fi[3]) * nc4[3];
        }
        ushort4 ib = *reinterpret_cast<const ushort4*>(lr +  768 + col);
        ushort4 ob = *reinterpret_cast<const ushort4*>(lr + 1024 + col);
        ushort4 ub = *reinterpret_cast<const ushort4*>(lr + 1280 + col);
        size_t iob = (size_t)gn * 768 + col;
        floatx4 i4 = *reinterpret_cast<const floatx4*>(iou_in + iob);
        floatx4 o4 = *reinterpret_cast<const floatx4*>(iou_in + iob + 256);
        floatx4 u4 = *reinterpret_cast<const floatx4*>(iou_in + iob + 512);
        float iv[4] = {bf2f(ib.x), bf2f(ib.y), bf2f(ib.z), bf2f(ib.w)};
        float ov[4] = {bf2f(ob.x), bf2f(ob.y), bf2f(ob.z), bf2f(ob.w)};
        float uv[4] = {bf2f(ub.x), bf2f(ub.y), bf2f(ub.z), bf2f(ub.w)};
        floatx4 cc, hh;
        #pragma unroll
        for (int r = 0; r < 4; ++r) {
            float c = sigf(iv[r] + 2.0f * i4[r]) * tanhfast(uv[r] + 2.0f * u4[r])
                      + cagg[r];
            cc[r] = c;
            hh[r] = sigf(ov[r] + 2.0f * o4[r]) * tanhfast(c);
        }
        *reinterpret_cast<floatx4*>(out + (size_t)gn * HD + col) = hh;
        *reinterpret_cast<floatx4*>(out + (size_t)(NN + gn) * HD + col) = cc;
    }
}

// ===========================================================================
// FALLBACK (r8 fused, verified): used when ws too small for split.
// ===========================================================================
__global__ void prep_fused32(const float* __restrict__ U_f,
                             const float* __restrict__ U_iou,
                             unsigned short* __restrict__ wsB) {
    int idx = blockIdx.x * 256 + threadIdx.x;
    int lane = idx & 63;
    int ks   = (idx >> 6) & 15;
    int tile = (idx >> 10) & 31;
    int d    = idx >> 15;
    if (d >= NCH) return;
    int col = tile * 32 + (lane & 31);
    int k0  = ks * 16 + (lane >> 5) * 8;
    const float* src = (col < 256)
        ? (U_f   + (((size_t)d * 256 + col)         * 256 + k0))
        : (U_iou + (((size_t)d * 768 + (col - 256)) * 256 + k0));
    shortx8 o;
    #pragma unroll
    for (int e = 0; e < 8; ++e) o[e] = (short)f2bf(src[e]);
    reinterpret_cast<shortx8*>(wsB)[idx] = o;
}

__global__ __launch_bounds__(512, 4) void fused_main(
    const float* __restrict__ nh, const float* __restrict__ ncc,
    const float* __restrict__ f_in, const float* __restrict__ iou_in,
    const unsigned short* __restrict__ wsB, float* __restrict__ out)
{
    __shared__ unsigned short sA[NCH * 32 * 32 * 8];
    const int tid  = threadIdx.x;
    const int nb   = blockIdx.x * 32;
    const int lane = tid & 63;
    const int cg   = tid >> 6;
    const int nl   = lane & 31;
    const int hi   = lane >> 5;
    const int colb = cg * 32 + hi * 4;
    const shortx8* Bfr = reinterpret_cast<const shortx8*>(wsB);
    #pragma unroll
    for (int i = 0; i < 6; ++i) {
        int c = i * 512 + tid;
        int d = c >> 10, node = (c >> 5) & 31, slot = c & 31;
        int gn = nb + node;
        shortx8 o;
        if (gn < NN) {
            const float4* q = reinterpret_cast<const float4*>(
                nh + ((size_t)gn * (NCH * HD) + d * HD + slot * 8));
            float4 a = q[0], b = q[1];
            union { uint32_t u[4]; shortx8 v; } t;
            t.u[0] = cvtpk(a.x, a.y); t.u[1] = cvtpk(a.z, a.w);
            t.u[2] = cvtpk(b.x, b.y); t.u[3] = cvtpk(b.z, b.w);
            o = t.v;
        } else {
            for (int e = 0; e < 8; ++e) o[e] = 0;
        }
        int idx = (d * 32 + node) * 32 + (slot ^ (node & 7));
        *reinterpret_cast<shortx8*>(&sA[idx * 8]) = o;
    }
    __syncthreads();
    const int  n     = nb + nl;
    const bool valid = (n < NN);
    const int  nc_   = valid ? n : (NN - 1);
    ushort4 finb[4];
    #pragma unroll
    for (int q = 0; q < 4; ++q) {
        floatx4 v = *reinterpret_cast<const floatx4*>(
            f_in + (size_t)nc_ * HD + colb + q * 8);
        finb[q] = ushort4{f2bf(v[0]), f2bf(v[1]), f2bf(v[2]), f2bf(v[3])};
    }
    float cagg[16];
    #pragma unroll
    for (int t = 0; t < 16; ++t) cagg[t] = 0.0f;
    floatx16 accI, accO, accU;
    #pragma unroll
    for (int t = 0; t < 16; ++t) { accI[t] = 0.f; accO[t] = 0.f; accU[t] = 0.f; }
    const int nsw = nl & 7;
    #pragma unroll 1
    for (int d = 0; d < NCH; ++d) {
        floatx16 accF;
        #pragma unroll
        for (int t = 0; t < 16; ++t) accF[t] = 0.0f;
        #pragma unroll 2
        for (int ks = 0; ks < 16; ++ks) {
            shortx8 aF = Bfr[((d * 32 +      cg) * 16 + ks) * 64 + lane];
            shortx8 aI = Bfr[((d * 32 +  8 + cg) * 16 + ks) * 64 + lane];
            shortx8 aO = Bfr[((d * 32 + 16 + cg) * 16 + ks) * 64 + lane];
            shortx8 aU = Bfr[((d * 32 + 24 + cg) * 16 + ks) * 64 + lane];
            int ch = (ks * 2 + hi) ^ nsw;
            shortx8 b = *reinterpret_cast<const shortx8*>(
                &sA[((d * 32 + nl) * 32 + ch) * 8]);
            accF = mfma32(aF, b, accF);
            accI = mfma32(aI, b, accI);
            accO = mfma32(aO, b, accO);
            accU = mfma32(aU, b, accU);
        }
        #pragma unroll
        for (int q = 0; q < 4; ++q) {
            floatx4 ncr = *reinterpret_cast<const floatx4*>(
                ncc + (size_t)nc_ * (NCH * HD) + d * HD + colb + q * 8);
            cagg[q*4+0] += sigf(accF[q*4+0] + bf2f(finb[q].x)) * ncr[0];
            cagg[q*4+1] += sigf(accF[q*4+1] + bf2f(finb[q].y)) * ncr[1];
            cagg[q*4+2] += sigf(accF[q*4+2] + bf2f(finb[q].z)) * ncr[2];
            cagg[q*4+3] += sigf(accF[q*4+3] + bf2f(finb[q].w)) * ncr[3];
        }
    }
    if (valid) {
        #pragma unroll
        for (int q = 0; q < 4; ++q) {
            int col = colb + q * 8;
            size_t base = (size_t)n * 768 + col;
            floatx4 i4 = *reinterpret_cast<const floatx4*>(iou_in + base);
            floatx4 o4 = *reinterpret_cast<const floatx4*>(iou_in + base + 256);
            floatx4 u4 = *reinterpret_cast<const floatx4*>(iou_in + base + 512);
            floatx4 cc, hh;
            #pragma unroll
            for (int r = 0; r < 4; ++r) {
                int t = q * 4 + r;
                float c = sigf(accI[t] + 2.f*i4[r]) * tanhfast(accU[t] + 2.f*u4[r])
                          + cagg[t];
                cc[r] = c;
                hh[r] = sigf(accO[t] + 2.f*o4[r]) * tanhfast(c);
            }
            *reinterpret_cast<floatx4*>(out + (size_t)n * HD + col) = hh;
            *reinterpret_cast<floatx4*>(out + (size_t)(NN + n) * HD + col) = cc;
        }
    }
}

// ===========================================================================
extern "C" void kernel_launch(void* const* d_in, const int* in_sizes, int n_in,
                              void* d_out, int out_size, void* d_ws, size_t ws_size,
                              hipStream_t stream) {
    const float* nh     = (const float*)d_in[0];
    const float* ncc    = (const float*)d_in[1];
    const float* f_in   = (const float*)d_in[2];
    const float* iou_in = (const float*)d_in[3];
    const float* U_f    = (const float*)d_in[4];
    const float* U_iou  = (const float*)d_in[5];
    unsigned short* wsB = (unsigned short*)d_ws;

    const size_t FRAG_BYTES = (size_t)98304 * 16;    // 1.5 MiB
    const size_t DATA_OFF   = (size_t)2 << 20;       // per-chunk data at +2 MiB

    long long cmax = 0;
    if (ws_size > DATA_OFF)
        cmax = (long long)((ws_size - DATA_OFF) / 4608);   // 1536B nh + 3072B logits
    cmax = (cmax / 128) * 128;

    if (cmax >= 128) {
        hipLaunchKernelGGL(prep_split, dim3(384), dim3(256), 0, stream,
                           U_f, U_iou, wsB);
        unsigned short* nhswz  = (unsigned short*)((char*)d_ws + DATA_OFF);
        unsigned short* logits = nhswz + (size_t)cmax * 768;
        int base = 0;
        while (base < NN) {
            long long rem = NN - base;
            int count = (int)(rem < cmax ? rem : cmax);

            int cgrid = (count * 96 + 255) / 256;
            if (cgrid > 2048) cgrid = 2048;
            hipLaunchKernelGGL(conv_nh, dim3(cgrid), dim3(256), 0, stream,
                               nh, nhswz, base, count);

            int nmb = (count + 127) / 128;
            hipLaunchKernelGGL(gemm_logits, dim3(nmb * 6), dim3(512), 0,
                               stream, nhswz, wsB, logits, count);

            int ewgrid = (count * 64 + 255) / 256;
            if (ewgrid > 2048) ewgrid = 2048;
            hipLaunchKernelGGL(ew_kernel, dim3(ewgrid), dim3(256), 0, stream,
                               logits, ncc, f_in, iou_in, (float*)d_out,
                               base, count);
            base += count;
        }
    } else if (ws_size >= FRAG_BYTES) {
        hipLaunchKernelGGL(prep_fused32, dim3(384), dim3(256), 0, stream,
                           U_f, U_iou, wsB);
        hipLaunchKernelGGL(fused_main, dim3((NN + 31) / 32), dim3(512), 0,
                           stream, nh, ncc, f_in, iou_in, wsB, (float*)d_out);
    }
}